// Round 2
// baseline (343.171 us; speedup 1.0000x reference)
//
#include <hip/hip_runtime.h>
#include <stdint.h>

#define HW   1369      // 37*37 output pixels
#define QW   39        // padded row width
#define QP   1616      // padded plane rows per (b) in Xp (max index 1615)
#define QT   1536      // q rows in x1 (12 tiles * 128)
#define CIN  1024
#define CMID 512
#define KTOT 9216      // 9 * 1024

typedef float  f32x4  __attribute__((ext_vector_type(4)));
typedef __bf16 bf16x8 __attribute__((ext_vector_type(8)));

__device__ __forceinline__ uint16_t f2bf(float f) {
  uint32_t u = __float_as_uint(f);
  u += 0x7fffu + ((u >> 16) & 1u);
  return (uint16_t)(u >> 16);
}

// global -> LDS direct copy, 16B per lane. LDS dest must be wave-uniform base;
// HW writes base + lane*16. (Generic->as3 via low-32-bit truncation: LDS
// generic addrs are aperture_hi | lds_offset on gfx9+.)
__device__ __forceinline__ void gll16(const void* g, void* l) {
  const __attribute__((address_space(1))) uint32_t* ga =
      (const __attribute__((address_space(1))) uint32_t*)(uintptr_t)g;
  __attribute__((address_space(3))) uint32_t* la =
      (__attribute__((address_space(3))) uint32_t*)(uint32_t)(uintptr_t)l;
  __builtin_amdgcn_global_load_lds(ga, la, 16, 0, 0);
}

// ---------- prep: fmap [b][c][h][w] f32 -> Xp [b][q][c] bf16 (padded, zeroed border) ----------
__global__ void k_pad_transpose(const float* __restrict__ fmap, uint16_t* __restrict__ Xp) {
  __shared__ float t[32][33];
  const int b = blockIdx.z;
  const int c0 = blockIdx.y * 32;
  const int p0 = blockIdx.x * 32;
  const int tx = threadIdx.x, ty = threadIdx.y;
  const float* src = fmap + ((size_t)b * CIN + c0) * HW + p0;
#pragma unroll
  for (int i = 0; i < 4; ++i) {
    int cc = ty + i * 8;
    t[cc][tx] = (p0 + tx < HW) ? src[(size_t)cc * HW + tx] : 0.f;
  }
  __syncthreads();
#pragma unroll
  for (int i = 0; i < 4; ++i) {
    int pl = ty + i * 8;
    int p = p0 + pl;
    if (p < HW) {
      int h = p / 37, w = p - h * 37;
      int q = (h + 1) * QW + (w + 1);
      Xp[((size_t)b * QP + q) * CIN + c0 + tx] = f2bf(t[tx][pl]);
    }
  }
}

// ---------- prep: W1 [o][c][3][3] f32 -> Apk [o][r*1024+c] bf16 ----------
__global__ void k_pack_w1(const float* __restrict__ W1, uint16_t* __restrict__ Apk) {
  int idx = blockIdx.x * 256 + threadIdx.x;
  if (idx >= 512 * KTOT) return;
  int o = idx / KTOT, k = idx - o * KTOT;
  int r = k >> 10, c = k & 1023;
  Apk[idx] = f2bf(W1[((size_t)o * CIN + c) * 9 + r]);
}

// ---------- prep: W2 [120][512] f32 -> W2p [128][512] bf16 (rows 120..127 zero) ----------
__global__ void k_pack_w2(const float* __restrict__ W2, uint16_t* __restrict__ W2p) {
  int idx = blockIdx.x * 256 + threadIdx.x;  // 65536 total
  int j = idx >> 9, o = idx & 511;
  W2p[idx] = (j < 120) ? f2bf(W2[j * 512 + o]) : (uint16_t)0;
}

// ---------- conv1: D[q][o] = sum_k Xp[q+off(r)][c] * W1[o][k], +bias, ReLU6 -> x1 bf16 ----------
__global__ __launch_bounds__(256, 2) void k_conv1(
    const uint16_t* __restrict__ Xp, const uint16_t* __restrict__ Apk,
    const float* __restrict__ b1, uint16_t* __restrict__ x1) {
  __shared__ __align__(16) uint16_t lA[128 * 64];   // [q][k]
  __shared__ __align__(16) uint16_t lB[128 * 64];   // [o][k]
  const int tid = threadIdx.x;
  const int wid = tid >> 6, lane = tid & 63;
  const int b = blockIdx.z, o0 = blockIdx.y * 128, q0 = blockIdx.x * 128;
  const uint16_t* Xb = Xp + (size_t)b * QP * CIN;
  const int wm = wid >> 1, wn = wid & 1;
  const int lrow = lane & 15, lk = (lane >> 4) * 8;
  f32x4 acc[4][4] = {};

  for (int kt = 0; kt < 144; ++kt) {
    const int r = kt >> 4, c0 = (kt & 15) << 6;
    const int off = (r / 3) * QW + (r % 3);
#pragma unroll
    for (int i = 0; i < 4; ++i) {
      int wb = i * 256 + wid * 64;   // wave-uniform 16B-chunk base
      int chunk = wb + lane;
      int row = chunk >> 3, ch = chunk & 7;
      gll16(Xb + (size_t)(q0 + off + row) * CIN + c0 + ch * 8, lA + wb * 8);
      gll16(Apk + (size_t)(o0 + row) * KTOT + (r << 10) + c0 + ch * 8, lB + wb * 8);
    }
    __syncthreads();
#pragma unroll
    for (int kk = 0; kk < 2; ++kk) {
      bf16x8 av[4], bv[4];
#pragma unroll
      for (int mi = 0; mi < 4; ++mi)
        av[mi] = *(const bf16x8*)(lA + (wm * 64 + mi * 16 + lrow) * 64 + kk * 32 + lk);
#pragma unroll
      for (int ni = 0; ni < 4; ++ni)
        bv[ni] = *(const bf16x8*)(lB + (wn * 64 + ni * 16 + lrow) * 64 + kk * 32 + lk);
#pragma unroll
      for (int mi = 0; mi < 4; ++mi)
#pragma unroll
        for (int ni = 0; ni < 4; ++ni)
          acc[mi][ni] = __builtin_amdgcn_mfma_f32_16x16x32_bf16(av[mi], bv[ni], acc[mi][ni], 0, 0, 0);
    }
    __syncthreads();
  }

  const int qr = (lane >> 4) * 4;
#pragma unroll
  for (int ni = 0; ni < 4; ++ni) {
    int o = o0 + wn * 64 + ni * 16 + lrow;
    float bias = b1[o];
#pragma unroll
    for (int mi = 0; mi < 4; ++mi) {
#pragma unroll
      for (int v = 0; v < 4; ++v) {
        int q = q0 + wm * 64 + mi * 16 + qr + v;
        float x = acc[mi][ni][v] + bias;
        x = fminf(fmaxf(x, 0.f), 6.f);
        x1[((size_t)b * QT + q) * CMID + o] = f2bf(x);
      }
    }
  }
}

// ---------- conv2: out[b][h][w][j] = sum_o x1[q][o] * W2[j][o] + b2[j] ----------
__global__ __launch_bounds__(256, 2) void k_conv2(
    const uint16_t* __restrict__ x1, const uint16_t* __restrict__ W2p,
    const float* __restrict__ b2, float* __restrict__ out) {
  __shared__ __align__(16) uint16_t lA[128 * 64];
  __shared__ __align__(16) uint16_t lB[128 * 64];
  const int tid = threadIdx.x;
  const int wid = tid >> 6, lane = tid & 63;
  const int b = blockIdx.z, q0 = blockIdx.x * 128;
  const uint16_t* Ab = x1 + (size_t)b * QT * CMID;
  const int wm = wid >> 1, wn = wid & 1;
  const int lrow = lane & 15, lk = (lane >> 4) * 8;
  f32x4 acc[4][4] = {};

  for (int kt = 0; kt < 8; ++kt) {
    const int c0 = kt << 6;
#pragma unroll
    for (int i = 0; i < 4; ++i) {
      int wb = i * 256 + wid * 64;
      int chunk = wb + lane;
      int row = chunk >> 3, ch = chunk & 7;
      gll16(Ab + (size_t)(q0 + row) * CMID + c0 + ch * 8, lA + wb * 8);
      gll16(W2p + (size_t)row * CMID + c0 + ch * 8, lB + wb * 8);
    }
    __syncthreads();
#pragma unroll
    for (int kk = 0; kk < 2; ++kk) {
      bf16x8 av[4], bv[4];
#pragma unroll
      for (int mi = 0; mi < 4; ++mi)
        av[mi] = *(const bf16x8*)(lA + (wm * 64 + mi * 16 + lrow) * 64 + kk * 32 + lk);
#pragma unroll
      for (int ni = 0; ni < 4; ++ni)
        bv[ni] = *(const bf16x8*)(lB + (wn * 64 + ni * 16 + lrow) * 64 + kk * 32 + lk);
#pragma unroll
      for (int mi = 0; mi < 4; ++mi)
#pragma unroll
        for (int ni = 0; ni < 4; ++ni)
          acc[mi][ni] = __builtin_amdgcn_mfma_f32_16x16x32_bf16(av[mi], bv[ni], acc[mi][ni], 0, 0, 0);
    }
    __syncthreads();
  }

  const int qr = (lane >> 4) * 4;
#pragma unroll
  for (int ni = 0; ni < 4; ++ni) {
    int j = wn * 64 + ni * 16 + lrow;
    if (j < 120) {
      float bias = b2[j];
#pragma unroll
      for (int mi = 0; mi < 4; ++mi) {
#pragma unroll
        for (int v = 0; v < 4; ++v) {
          int q = q0 + wm * 64 + mi * 16 + qr + v;
          int h = q / QW, w = q - h * QW;
          if (h < 37 && w < 37) {
            out[((size_t)b * HW + h * 37 + w) * 120 + j] = acc[mi][ni][v] + bias;
          }
        }
      }
    }
  }
}

extern "C" void kernel_launch(void* const* d_in, const int* in_sizes, int n_in,
                              void* d_out, int out_size, void* d_ws, size_t ws_size,
                              hipStream_t stream) {
  const float* fmap = (const float*)d_in[0];
  const float* W1   = (const float*)d_in[1];
  const float* b1   = (const float*)d_in[2];
  const float* W2   = (const float*)d_in[3];
  const float* b2   = (const float*)d_in[4];
  float* out = (float*)d_out;

  uint8_t* ws = (uint8_t*)d_ws;
  const size_t XP_BYTES  = (size_t)16 * QP * CIN * 2;   // 52,953,088
  const size_t W1P_BYTES = (size_t)512 * KTOT * 2;      //  9,437,184
  const size_t W2P_BYTES = (size_t)128 * 512 * 2;       //    131,072
  uint16_t* Xp  = (uint16_t*)ws;
  uint16_t* Apk = (uint16_t*)(ws + XP_BYTES);
  uint16_t* W2p = (uint16_t*)(ws + XP_BYTES + W1P_BYTES);
  uint16_t* x1  = (uint16_t*)(ws + XP_BYTES + W1P_BYTES + W2P_BYTES);
  // total ws use: ~87.7 MB (x1 = 16*1536*512*2 = 25,165,824)

  hipMemsetAsync(Xp, 0, XP_BYTES, stream);
  k_pad_transpose<<<dim3(43, 32, 16), dim3(32, 8), 0, stream>>>(fmap, Xp);
  k_pack_w1<<<dim3((512 * KTOT + 255) / 256), dim3(256), 0, stream>>>(W1, Apk);
  k_pack_w2<<<dim3(256), dim3(256), 0, stream>>>(W2, W2p);
  k_conv1<<<dim3(12, 4, 16), dim3(256), 0, stream>>>(Xp, Apk, b1, x1);
  k_conv2<<<dim3(12, 1, 16), dim3(256), 0, stream>>>(x1, W2p, b2, out);
}